// Round 1
// baseline (506.169 us; speedup 1.0000x reference)
//
#include <hip/hip_runtime.h>
#include <math.h>

#define Bn 4
#define Tn 4096
#define En 256
#define An 64
#define LS 68   // LDS row stride in floats: 16B-aligned (68*4=272), bank step 4

// ---------------------------------------------------------------------------
// Kernel 1: QKV projection.  out[m][row][a] = emb[row][:] @ W[m][:,a] + b[m][a]
// grid: (B*T/64, 3), block 256.  64x64 output tile per block, K-loop over E.
// ---------------------------------------------------------------------------
__global__ __launch_bounds__(256) void proj_kernel(
    const float* __restrict__ emb,
    const float* __restrict__ Wq, const float* __restrict__ bq,
    const float* __restrict__ Wk, const float* __restrict__ bk,
    const float* __restrict__ Wv, const float* __restrict__ bv,
    float* __restrict__ qo, float* __restrict__ ko, float* __restrict__ vo)
{
    const int m = blockIdx.y;
    const float* __restrict__ W    = (m == 0) ? Wq : (m == 1 ? Wk : Wv);
    const float* __restrict__ bias = (m == 0) ? bq : (m == 1 ? bk : bv);
    float* __restrict__ out        = (m == 0) ? qo : (m == 1 ? ko : vo);

    const int row0   = blockIdx.x * 64;
    const int tid    = threadIdx.x;
    const int lane16 = tid & 15;   // i-fragment selector (rows i = lane16 + 16*ii)
    const int grp    = tid >> 4;   // a-fragment selector (cols a = grp*4 + jj)

    __shared__ float se[64 * LS];  // emb tile [row][e], stride LS
    __shared__ float sw[64 * LS];  // W   tile [e][a],   stride LS

    float acc[4][4];
#pragma unroll
    for (int i = 0; i < 4; i++)
#pragma unroll
        for (int j = 0; j < 4; j++) acc[i][j] = 0.f;

    for (int eb = 0; eb < En; eb += 64) {
        __syncthreads();
        {
            const int r  = tid >> 4;         // 0..15
            const int c4 = (tid & 15) * 4;   // 0..60
#pragma unroll
            for (int p = 0; p < 4; p++) {
                const int i = p * 16 + r;    // 0..63
                float4 t = *(const float4*)&emb[(size_t)(row0 + i) * En + eb + c4];
                *(float4*)&se[i * LS + c4] = t;
                float4 u = *(const float4*)&W[(size_t)(eb + i) * An + c4];
                *(float4*)&sw[i * LS + c4] = u;
            }
        }
        __syncthreads();
#pragma unroll 4
        for (int e4 = 0; e4 < 64; e4 += 4) {
            float4 ev[4], wv[4];
#pragma unroll
            for (int ii = 0; ii < 4; ii++)
                ev[ii] = *(const float4*)&se[(lane16 + 16 * ii) * LS + e4];
#pragma unroll
            for (int q = 0; q < 4; q++)
                wv[q] = *(const float4*)&sw[(e4 + q) * LS + grp * 4];
#pragma unroll
            for (int ii = 0; ii < 4; ii++) {
                const float ea[4] = {ev[ii].x, ev[ii].y, ev[ii].z, ev[ii].w};
#pragma unroll
                for (int q = 0; q < 4; q++) {
                    acc[ii][0] += ea[q] * wv[q].x;
                    acc[ii][1] += ea[q] * wv[q].y;
                    acc[ii][2] += ea[q] * wv[q].z;
                    acc[ii][3] += ea[q] * wv[q].w;
                }
            }
        }
    }

    const float4 bv4 = *(const float4*)&bias[grp * 4];
#pragma unroll
    for (int ii = 0; ii < 4; ii++) {
        const int row = row0 + lane16 + 16 * ii;
        float4 r;
        r.x = acc[ii][0] + bv4.x;
        r.y = acc[ii][1] + bv4.y;
        r.z = acc[ii][2] + bv4.z;
        r.w = acc[ii][3] + bv4.w;
        *(float4*)&out[(size_t)row * An + grp * 4] = r;
    }
}

// ---------------------------------------------------------------------------
// Kernel 2: flash-style causal attention, fp32.
// grid: (T/64, B), block 256.  One 64-query tile per block; online softmax.
// Thread fragment: S rows i = lane16 + 16*ii, S cols j = grp*4 + jj.
// O fragment:       rows i = lane16 + 16*ii, cols a = grp*4 + jj.
// ---------------------------------------------------------------------------
__global__ __launch_bounds__(256) void flash_kernel(
    const float* __restrict__ q, const float* __restrict__ k,
    const float* __restrict__ v, float* __restrict__ out)
{
    const int qt  = blockIdx.x;   // query tile 0..63
    const int b   = blockIdx.y;   // batch
    const int tid = threadIdx.x;
    const int lane16 = tid & 15;
    const int grp    = tid >> 4;

    const float scale = 0.125f;   // 1/sqrt(64)

    __shared__ float sq[64 * LS];   // Q tile [i][a] (pre-scaled)
    __shared__ float sk[64 * LS];   // K tile [j][a]
    __shared__ float sv[64 * LS];   // V tile [j][a]
    __shared__ float sp[64 * LS];   // S/P tile stored [j][i]
    __shared__ float sm[64], sl[64], salpha[64];
    __shared__ float red[4 * 64];

    // ---- load + scale Q tile ----
    {
        const size_t base = ((size_t)b * Tn + (size_t)qt * 64) * An;
        const int r  = tid >> 4;
        const int c4 = (tid & 15) * 4;
#pragma unroll
        for (int p = 0; p < 4; p++) {
            const int i = p * 16 + r;
            float4 t = *(const float4*)&q[base + (size_t)i * An + c4];
            t.x *= scale; t.y *= scale; t.z *= scale; t.w *= scale;
            *(float4*)&sq[i * LS + c4] = t;
        }
    }
    if (tid < 64) { sm[tid] = -INFINITY; sl[tid] = 0.f; }

    float o[4][4];
#pragma unroll
    for (int i = 0; i < 4; i++)
#pragma unroll
        for (int j = 0; j < 4; j++) o[i][j] = 0.f;

    for (int kt = 0; kt <= qt; kt++) {
        __syncthreads();   // prev PV done; Q/state ready on first iter
        // ---- stage K,V tiles ----
        {
            const size_t kbase = ((size_t)b * Tn + (size_t)kt * 64) * An;
            const int r  = tid >> 4;
            const int c4 = (tid & 15) * 4;
#pragma unroll
            for (int p = 0; p < 4; p++) {
                const int j = p * 16 + r;
                *(float4*)&sk[j * LS + c4] = *(const float4*)&k[kbase + (size_t)j * An + c4];
                *(float4*)&sv[j * LS + c4] = *(const float4*)&v[kbase + (size_t)j * An + c4];
            }
        }
        __syncthreads();

        // ---- S = Q K^T (per-thread 4x4 fragment) ----
        float s[4][4];
#pragma unroll
        for (int i = 0; i < 4; i++)
#pragma unroll
            for (int j = 0; j < 4; j++) s[i][j] = 0.f;

        for (int a4 = 0; a4 < 64; a4 += 4) {
            float4 qv[4], kv[4];
#pragma unroll
            for (int ii = 0; ii < 4; ii++)
                qv[ii] = *(const float4*)&sq[(lane16 + 16 * ii) * LS + a4];
#pragma unroll
            for (int jj = 0; jj < 4; jj++)
                kv[jj] = *(const float4*)&sk[(grp * 4 + jj) * LS + a4];
#pragma unroll
            for (int ii = 0; ii < 4; ii++)
#pragma unroll
                for (int jj = 0; jj < 4; jj++)
                    s[ii][jj] += qv[ii].x * kv[jj].x + qv[ii].y * kv[jj].y +
                                 qv[ii].z * kv[jj].z + qv[ii].w * kv[jj].w;
        }

        // ---- causal mask (diagonal tile only) ----
        if (kt == qt) {
#pragma unroll
            for (int ii = 0; ii < 4; ii++)
#pragma unroll
                for (int jj = 0; jj < 4; jj++)
                    if (grp * 4 + jj > lane16 + 16 * ii) s[ii][jj] = -INFINITY;
        }

        // ---- write S to LDS in [j][i] layout ----
#pragma unroll
        for (int jj = 0; jj < 4; jj++)
#pragma unroll
            for (int ii = 0; ii < 4; ii++)
                sp[(grp * 4 + jj) * LS + lane16 + 16 * ii] = s[ii][jj];
        __syncthreads();

        // ---- phase A: per-row partial max over 16 j's ----
        {
            const int i = tid & 63, c = tid >> 6;
            float pm = -INFINITY;
#pragma unroll
            for (int jj = 0; jj < 16; jj++)
                pm = fmaxf(pm, sp[(c * 16 + jj) * LS + i]);
            red[c * 64 + i] = pm;
        }
        __syncthreads();

        // ---- phase B: m/alpha update (one wave) ----
        if (tid < 64) {
            const int i = tid;
            const float tm = fmaxf(fmaxf(red[i], red[64 + i]), fmaxf(red[128 + i], red[192 + i]));
            const float mold = sm[i];
            const float mnew = fmaxf(mold, tm);
            sm[i] = mnew;
            salpha[i] = __expf(mold - mnew);
        }
        __syncthreads();

        // ---- phase C: P = exp(S - m), partial row sums; rescale O ----
        {
            const int i = tid & 63, c = tid >> 6;
            const float mnew = sm[i];
            float ps = 0.f;
#pragma unroll
            for (int jj = 0; jj < 16; jj++) {
                const int j = c * 16 + jj;
                const float p = __expf(sp[j * LS + i] - mnew);
                sp[j * LS + i] = p;
                ps += p;
            }
            red[c * 64 + i] = ps;
        }
        {
            const float a0 = salpha[lane16];
            const float a1 = salpha[lane16 + 16];
            const float a2 = salpha[lane16 + 32];
            const float a3 = salpha[lane16 + 48];
#pragma unroll
            for (int jj = 0; jj < 4; jj++) {
                o[0][jj] *= a0; o[1][jj] *= a1; o[2][jj] *= a2; o[3][jj] *= a3;
            }
        }
        __syncthreads();

        // ---- l update (wave 0) + PV accumulate (all threads) ----
        if (tid < 64) {
            const int i = tid;
            sl[i] = sl[i] * salpha[i] + (red[i] + red[64 + i] + red[128 + i] + red[192 + i]);
        }
        for (int j = 0; j < 64; j++) {
            const float4 vv = *(const float4*)&sv[j * LS + grp * 4];
            const float p0 = sp[j * LS + lane16];
            const float p1 = sp[j * LS + lane16 + 16];
            const float p2 = sp[j * LS + lane16 + 32];
            const float p3 = sp[j * LS + lane16 + 48];
            o[0][0] += p0 * vv.x; o[0][1] += p0 * vv.y; o[0][2] += p0 * vv.z; o[0][3] += p0 * vv.w;
            o[1][0] += p1 * vv.x; o[1][1] += p1 * vv.y; o[1][2] += p1 * vv.z; o[1][3] += p1 * vv.w;
            o[2][0] += p2 * vv.x; o[2][1] += p2 * vv.y; o[2][2] += p2 * vv.z; o[2][3] += p2 * vv.w;
            o[3][0] += p3 * vv.x; o[3][1] += p3 * vv.y; o[3][2] += p3 * vv.z; o[3][3] += p3 * vv.w;
        }
    }

    __syncthreads();
    // ---- epilogue: divide by l, store ----
    {
        const size_t obase = ((size_t)b * Tn + (size_t)qt * 64) * An;
#pragma unroll
        for (int ii = 0; ii < 4; ii++) {
            const int i = lane16 + 16 * ii;
            const float inv = 1.f / sl[i];
            float4 r;
            r.x = o[ii][0] * inv; r.y = o[ii][1] * inv;
            r.z = o[ii][2] * inv; r.w = o[ii][3] * inv;
            *(float4*)&out[obase + (size_t)i * An + grp * 4] = r;
        }
    }
}

// ---------------------------------------------------------------------------
extern "C" void kernel_launch(void* const* d_in, const int* in_sizes, int n_in,
                              void* d_out, int out_size, void* d_ws, size_t ws_size,
                              hipStream_t stream) {
    const float* emb = (const float*)d_in[0];
    const float* Wk  = (const float*)d_in[1];
    const float* bk  = (const float*)d_in[2];
    const float* Wq  = (const float*)d_in[3];
    const float* bq  = (const float*)d_in[4];
    const float* Wv  = (const float*)d_in[5];
    const float* bv  = (const float*)d_in[6];
    float* out = (float*)d_out;

    float* ws = (float*)d_ws;
    const size_t BTA = (size_t)Bn * Tn * An;   // 1,048,576 floats
    float* q = ws;
    float* k = ws + BTA;
    float* v = ws + 2 * BTA;

    proj_kernel<<<dim3(Bn * Tn / 64, 3), 256, 0, stream>>>(
        emb, Wq, bq, Wk, bk, Wv, bv, q, k, v);
    flash_kernel<<<dim3(Tn / 64, Bn), 256, 0, stream>>>(q, k, v, out);
}

// Round 2
// 155.500 us; speedup vs baseline: 3.2551x; 3.2551x over previous
//
#include <hip/hip_runtime.h>
#include <math.h>

#define Bn 4
#define Tn 4096
#define En 256
#define An 64
#define LSB 72   // bf16 LDS row stride: 144 B = 36 dwords -> 4-bank shift/row, 16B aligned

typedef __attribute__((ext_vector_type(8))) short short8;
typedef __attribute__((ext_vector_type(8))) __bf16 bf16x8;
typedef __attribute__((ext_vector_type(4))) float f32x4;

__device__ __forceinline__ f32x4 mfma16(short8 a, short8 b, f32x4 c) {
    return __builtin_amdgcn_mfma_f32_16x16x32_bf16(
        __builtin_bit_cast(bf16x8, a), __builtin_bit_cast(bf16x8, b), c, 0, 0, 0);
}
__device__ __forceinline__ unsigned short f2bf(float x) {   // RNE fp32->bf16
    unsigned int u = __builtin_bit_cast(unsigned int, x);
    u += 0x7fffu + ((u >> 16) & 1u);
    return (unsigned short)(u >> 16);
}
__device__ __forceinline__ float bf2f(unsigned short h) {
    return __builtin_bit_cast(float, (unsigned int)h << 16);
}

// ---------------------------------------------------------------------------
// Kernel 0: transpose W[e][a] fp32 -> W_t[m][a][e] bf16 (B-operand-friendly).
// ---------------------------------------------------------------------------
__global__ __launch_bounds__(256) void prep_kernel(
    const float* __restrict__ Wq, const float* __restrict__ Wk, const float* __restrict__ Wv,
    unsigned short* __restrict__ W_t)
{
    const int m = blockIdx.x;
    const float* __restrict__ W = (m == 0) ? Wq : (m == 1 ? Wk : Wv);
    __shared__ unsigned short tr[64 * 264];
    const int tid = threadIdx.x;
    for (int it = 0; it < 16; it++) {
        const int idx = it * 256 + tid;       // 0..4095 = e*16 + a4grp
        const int e  = idx >> 4;
        const int a4 = (idx & 15) * 4;
        float4 w = *(const float4*)&W[(size_t)e * An + a4];
        tr[(a4 + 0) * 264 + e] = f2bf(w.x);
        tr[(a4 + 1) * 264 + e] = f2bf(w.y);
        tr[(a4 + 2) * 264 + e] = f2bf(w.z);
        tr[(a4 + 3) * 264 + e] = f2bf(w.w);
    }
    __syncthreads();
    const int a  = tid & 63;
    const int eg = (tid >> 6) * 64;
#pragma unroll
    for (int j = 0; j < 8; j++)
        *(short8*)&W_t[(size_t)(m * 64 + a) * En + eg + j * 8] =
            *(const short8*)&tr[a * 264 + eg + j * 8];
}

// ---------------------------------------------------------------------------
// Kernel 1: fused QKV projection, bf16 MFMA.  One block = 64 rows x all 192
// output cols (12 n-tiles).  Wave w owns rows w*16..+15.  K=256 in 8 chunks.
// Outputs: q bf16 [b][t][a] pre-scaled by 0.125;  k bf16 [b][t][a];
//          v_t bf16 [b][a][t] (transposed via LDS for PV B-fragments).
// ---------------------------------------------------------------------------
__global__ __launch_bounds__(256, 2) void proj_kernel(
    const float* __restrict__ emb, const unsigned short* __restrict__ W_t,
    const float* __restrict__ bq, const float* __restrict__ bk, const float* __restrict__ bv,
    unsigned short* __restrict__ q, unsigned short* __restrict__ k, unsigned short* __restrict__ v_t)
{
    const int tid  = threadIdx.x;
    const int wave = tid >> 6, lane = tid & 63, quad = lane >> 4, l15 = lane & 15;
    const int row0  = blockIdx.x * 64;      // global row in [0, B*T)
    const int b     = row0 >> 12;
    const int trow0 = row0 & 4095;

    __shared__ unsigned short vtr[64 * LSB];

    // A-fragments: emb rows (fp32 -> bf16), A[m=l15][k=quad*8+j]
    short8 A[8];
    {
        const float* erow = emb + (size_t)(row0 + wave * 16 + l15) * En;
#pragma unroll
        for (int c = 0; c < 8; c++) {
            const float* p = erow + c * 32 + quad * 8;
            float4 f0 = *(const float4*)p;
            float4 f1 = *(const float4*)(p + 4);
            A[c] = (short8){(short)f2bf(f0.x), (short)f2bf(f0.y), (short)f2bf(f0.z), (short)f2bf(f0.w),
                            (short)f2bf(f1.x), (short)f2bf(f1.y), (short)f2bf(f1.z), (short)f2bf(f1.w)};
        }
    }

    f32x4 acc[12];
#pragma unroll
    for (int nt = 0; nt < 12; nt++) acc[nt] = (f32x4){0.f, 0.f, 0.f, 0.f};

#pragma unroll
    for (int nt = 0; nt < 12; nt++) {
        const unsigned short* wb =
            W_t + (size_t)((nt >> 2) * 64 + (nt & 3) * 16 + l15) * En + quad * 8;
#pragma unroll
        for (int c = 0; c < 8; c++) {
            short8 bf = *(const short8*)(wb + c * 32);
            acc[nt] = mfma16(A[c], bf, acc[nt]);
        }
    }

    const float QS = 0.125f;   // 1/sqrt(A) folded into Q
#pragma unroll
    for (int nt = 0; nt < 12; nt++) {
        const int m  = nt >> 2;
        const int al = (nt & 3) * 16 + l15;
        const float bsv = ((m == 0) ? bq : (m == 1) ? bk : bv)[al];
#pragma unroll
        for (int rg = 0; rg < 4; rg++) {
            const int row_l = wave * 16 + quad * 4 + rg;   // C/D: row=quad*4+reg, col=l15
            const float val = acc[nt][rg] + bsv;
            if (m == 0)      q[(size_t)(row0 + row_l) * An + al] = f2bf(val * QS);
            else if (m == 1) k[(size_t)(row0 + row_l) * An + al] = f2bf(val);
            else             vtr[al * LSB + row_l] = f2bf(val);
        }
    }
    __syncthreads();
    {   // flush V^T tile: v_t[b][a][t]
        const int a  = tid >> 2;
        const int tg = (tid & 3) * 16;
        unsigned short* dst = v_t + (size_t)(b * 64 + a) * Tn + trow0 + tg;
        *(short8*)dst       = *(const short8*)&vtr[a * LSB + tg];
        *(short8*)(dst + 8) = *(const short8*)&vtr[a * LSB + tg + 8];
    }
}

// ---------------------------------------------------------------------------
// Kernel 2: flash attention, bf16 MFMA, 2 kv-stripes per query tile.
// grid (128, 4): u=blockIdx.x -> stripe s=u&1, tile qtr=u>>1; batches {2,3}
// reverse tile order so CU-paired blocks get qt and 63-qt (balance).
// Block = 4 waves; wave w owns q-rows w*16..+15 of the 64-row tile.
// Online softmax state per (quad,reg) row, replicated across 16 lanes.
// ---------------------------------------------------------------------------
__global__ __launch_bounds__(256, 2) void flash_kernel(
    const unsigned short* __restrict__ q, const unsigned short* __restrict__ k,
    const unsigned short* __restrict__ v_t,
    unsigned short* __restrict__ Opart, float* __restrict__ ml)
{
    const int b   = blockIdx.y;
    const int u   = blockIdx.x;
    const int s   = u & 1;
    const int qtr = u >> 1;
    const int qt  = (b >= 2) ? (63 - qtr) : qtr;

    const int tid  = threadIdx.x;
    const int wave = tid >> 6, lane = tid & 63, quad = lane >> 4, l15 = lane & 15;

    __shared__ unsigned short sk[64 * LSB];        // K tile [kv][a]
    __shared__ unsigned short sv[64 * LSB];        // V^T tile [a][kv]
    __shared__ unsigned short sp[4 * 16 * LSB];    // per-wave P round-trip [row][kv]
    unsigned short* spw = &sp[wave * 16 * LSB];

    // persistent Q A-fragments (bf16, pre-scaled)
    const unsigned short* qrow = q + ((size_t)b * Tn + (size_t)qt * 64 + wave * 16 + l15) * An;
    const short8 aq0 = *(const short8*)(qrow + quad * 8);
    const short8 aq1 = *(const short8*)(qrow + 32 + quad * 8);

    float m_r[4] = {-__builtin_inff(), -__builtin_inff(), -__builtin_inff(), -__builtin_inff()};
    float l_r[4] = {0.f, 0.f, 0.f, 0.f};
    f32x4 O[4] = {{0,0,0,0},{0,0,0,0},{0,0,0,0},{0,0,0,0}};

    const int r_st = tid >> 2;            // staging: row 0..63
    const int c_st = (tid & 3) * 16;      // staging: col group
    const unsigned short* kbase = k   + (size_t)b * Tn * An;
    const unsigned short* vbase = v_t + (size_t)b * An * Tn;

    for (int t = s; t <= qt; t += 2) {
        __syncthreads();
        {   // stage K and V^T tiles (bf16 copies, 32B per thread per array)
            const unsigned short* kp = kbase + ((size_t)t * 64 + r_st) * An + c_st;
            *(short8*)&sk[r_st * LSB + c_st]     = *(const short8*)kp;
            *(short8*)&sk[r_st * LSB + c_st + 8] = *(const short8*)(kp + 8);
            const unsigned short* vp = vbase + (size_t)r_st * Tn + (size_t)t * 64 + c_st;
            *(short8*)&sv[r_st * LSB + c_st]     = *(const short8*)vp;
            *(short8*)&sv[r_st * LSB + c_st + 8] = *(const short8*)(vp + 8);
        }
        __syncthreads();

        // ---- S = Q K^T : 8 MFMA ----
        f32x4 S[4] = {{0,0,0,0},{0,0,0,0},{0,0,0,0},{0,0,0,0}};
#pragma unroll
        for (int nt = 0; nt < 4; nt++) {
            const short8 b0 = *(const short8*)&sk[(nt * 16 + l15) * LSB + quad * 8];
            const short8 b1 = *(const short8*)&sk[(nt * 16 + l15) * LSB + 32 + quad * 8];
            S[nt] = mfma16(aq0, b0, S[nt]);
            S[nt] = mfma16(aq1, b1, S[nt]);
        }

        // ---- causal mask on diagonal tile ----
        if (t == qt) {
            const int row_l = wave * 16 + quad * 4;
#pragma unroll
            for (int nt = 0; nt < 4; nt++)
#pragma unroll
                for (int rg = 0; rg < 4; rg++)
                    if (nt * 16 + l15 > row_l + rg) S[nt][rg] = -__builtin_inff();
        }

        // ---- online softmax: row max / alpha ----
        float alpha[4];
#pragma unroll
        for (int rg = 0; rg < 4; rg++) {
            float mt = fmaxf(fmaxf(S[0][rg], S[1][rg]), fmaxf(S[2][rg], S[3][rg]));
            mt = fmaxf(mt, __shfl_xor(mt, 1));
            mt = fmaxf(mt, __shfl_xor(mt, 2));
            mt = fmaxf(mt, __shfl_xor(mt, 4));
            mt = fmaxf(mt, __shfl_xor(mt, 8));
            const float mn = fmaxf(m_r[rg], mt);
            alpha[rg] = __expf(m_r[rg] - mn);
            m_r[rg] = mn;
        }

        // ---- P = exp(S - m), row sums, l update ----
#pragma unroll
        for (int rg = 0; rg < 4; rg++) {
            float acc = 0.f;
#pragma unroll
            for (int nt = 0; nt < 4; nt++) {
                const float p = __expf(S[nt][rg] - m_r[rg]);
                S[nt][rg] = p;
                acc += p;
            }
            acc += __shfl_xor(acc, 1);
            acc += __shfl_xor(acc, 2);
            acc += __shfl_xor(acc, 4);
            acc += __shfl_xor(acc, 8);
            l_r[rg] = l_r[rg] * alpha[rg] + acc;
        }

        // ---- rescale O; P -> LDS (C/D layout -> [row][kv] bf16) ----
#pragma unroll
        for (int nt = 0; nt < 4; nt++)
#pragma unroll
            for (int rg = 0; rg < 4; rg++) {
                O[nt][rg] *= alpha[rg];
                spw[(quad * 4 + rg) * LSB + nt * 16 + l15] = f2bf(S[nt][rg]);
            }

        // ---- P A-fragments; PV: 8 MFMA ----
        const short8 ap0 = *(const short8*)&spw[l15 * LSB + quad * 8];
        const short8 ap1 = *(const short8*)&spw[l15 * LSB + 32 + quad * 8];
#pragma unroll
        for (int nt = 0; nt < 4; nt++) {
            const short8 b0 = *(const short8*)&sv[(nt * 16 + l15) * LSB + quad * 8];
            const short8 b1 = *(const short8*)&sv[(nt * 16 + l15) * LSB + 32 + quad * 8];
            O[nt] = mfma16(ap0, b0, O[nt]);
            O[nt] = mfma16(ap1, b1, O[nt]);
        }
    }

    // ---- store partials (bf16 O~, fp32 m/l) ----
    const size_t ob = ((size_t)(b * 64 + qt) * 2 + s) * 4096;
#pragma unroll
    for (int nt = 0; nt < 4; nt++)
#pragma unroll
        for (int rg = 0; rg < 4; rg++)
            Opart[ob + (size_t)(wave * 16 + quad * 4 + rg) * 64 + nt * 16 + l15] = f2bf(O[nt][rg]);
    if (l15 == 0) {
        const int mlb = ((b * 64 + qt) * 2 + s) * 128;
#pragma unroll
        for (int rg = 0; rg < 4; rg++) {
            ml[mlb + wave * 16 + quad * 4 + rg]      = m_r[rg];
            ml[mlb + 64 + wave * 16 + quad * 4 + rg] = l_r[rg];
        }
    }
}

// ---------------------------------------------------------------------------
// Kernel 3: merge the two kv-stripe partials -> out fp32 [b][t][a].
// ---------------------------------------------------------------------------
__global__ __launch_bounds__(256) void merge_kernel(
    const unsigned short* __restrict__ Opart, const float* __restrict__ ml,
    float* __restrict__ out)
{
    const int qt = blockIdx.x, b = blockIdx.y;
    const int tid = threadIdx.x;
    const int r   = tid >> 2;
    const int c16 = (tid & 3) * 16;
    const int mlb = (b * 64 + qt) * 2 * 128;
    const float m0 = ml[mlb + r],       l0 = ml[mlb + 64 + r];
    const float m1 = ml[mlb + 128 + r], l1 = ml[mlb + 192 + r];
    const float m  = fmaxf(m0, m1);
    const float a0 = __expf(m0 - m);
    const float a1 = __expf(m1 - m);
    const float inv = 1.f / (l0 * a0 + l1 * a1);
    const size_t p0 = ((size_t)(b * 64 + qt) * 2) * 4096 + (size_t)r * 64 + c16;
    const size_t p1 = p0 + 4096;
    float* op = out + ((size_t)b * Tn + (size_t)qt * 64 + r) * An + c16;
    const short8 o0a = *(const short8*)&Opart[p0];
    const short8 o0b = *(const short8*)&Opart[p0 + 8];
    const short8 o1a = *(const short8*)&Opart[p1];
    const short8 o1b = *(const short8*)&Opart[p1 + 8];
#pragma unroll
    for (int j = 0; j < 8; j++) {
        op[j]     = (bf2f((unsigned short)o0a[j]) * a0 + bf2f((unsigned short)o1a[j]) * a1) * inv;
        op[j + 8] = (bf2f((unsigned short)o0b[j]) * a0 + bf2f((unsigned short)o1b[j]) * a1) * inv;
    }
}

// ---------------------------------------------------------------------------
extern "C" void kernel_launch(void* const* d_in, const int* in_sizes, int n_in,
                              void* d_out, int out_size, void* d_ws, size_t ws_size,
                              hipStream_t stream) {
    const float* emb = (const float*)d_in[0];
    const float* Wk  = (const float*)d_in[1];
    const float* bk  = (const float*)d_in[2];
    const float* Wq  = (const float*)d_in[3];
    const float* bq  = (const float*)d_in[4];
    const float* Wv  = (const float*)d_in[5];
    const float* bv  = (const float*)d_in[6];
    float* out = (float*)d_out;

    char* ws = (char*)d_ws;
    const size_t MB = 1024 * 1024;
    unsigned short* q     = (unsigned short*)(ws);                      // 2 MB
    unsigned short* k     = (unsigned short*)(ws + 2 * MB);             // 2 MB
    unsigned short* v_t   = (unsigned short*)(ws + 4 * MB);             // 2 MB
    unsigned short* W_t   = (unsigned short*)(ws + 6 * MB);             // 96 KB
    unsigned short* Opart = (unsigned short*)(ws + 6 * MB + 98304);     // 4 MB
    float*          ml    = (float*)(ws + 10 * MB + 98304);             // 256 KB

    prep_kernel<<<3, 256, 0, stream>>>(Wq, Wk, Wv, W_t);
    proj_kernel<<<256, 256, 0, stream>>>(emb, W_t, bq, bk, bv, q, k, v_t);
    flash_kernel<<<dim3(128, 4), 256, 0, stream>>>(q, k, v_t, Opart, ml);
    merge_kernel<<<dim3(64, 4), 256, 0, stream>>>(Opart, ml, out);
}

// Round 3
// 150.228 us; speedup vs baseline: 3.3693x; 1.0351x over previous
//
#include <hip/hip_runtime.h>
#include <math.h>

#define Bn 4
#define Tn 4096
#define En 256
#define An 64

typedef __attribute__((ext_vector_type(8))) short short8;
typedef __attribute__((ext_vector_type(8))) __bf16 bf16x8;
typedef __attribute__((ext_vector_type(4))) float f32x4;
typedef __attribute__((ext_vector_type(4))) int int4v;
typedef __attribute__((ext_vector_type(4))) short short4v;

__device__ __forceinline__ f32x4 mfma16(short8 a, short8 b, f32x4 c) {
    return __builtin_amdgcn_mfma_f32_16x16x32_bf16(
        __builtin_bit_cast(bf16x8, a), __builtin_bit_cast(bf16x8, b), c, 0, 0, 0);
}
__device__ __forceinline__ unsigned short f2bf(float x) {   // RNE fp32->bf16
    unsigned int u = __builtin_bit_cast(unsigned int, x);
    u += 0x7fffu + ((u >> 16) & 1u);
    return (unsigned short)(u >> 16);
}
__device__ __forceinline__ float bf2f(unsigned short h) {
    return __builtin_bit_cast(float, (unsigned int)h << 16);
}
__device__ __forceinline__ unsigned int packbf2(float lo, float hi) {
    return (unsigned int)f2bf(lo) | ((unsigned int)f2bf(hi) << 16);
}

// ---------------------------------------------------------------------------
// Kernel 0: transpose W[e][a] fp32 -> W_t[m][a][e] bf16.  grid (3, 16).
// ---------------------------------------------------------------------------
__global__ __launch_bounds__(256) void prep_kernel(
    const float* __restrict__ Wq, const float* __restrict__ Wk, const float* __restrict__ Wv,
    unsigned short* __restrict__ W_t)
{
    const int m  = blockIdx.x;
    const int es = blockIdx.y;          // e-slice of 16
    const float* __restrict__ W = (m == 0) ? Wq : (m == 1 ? Wk : Wv);
    __shared__ unsigned short tr[64][18];
    const int tid = threadIdx.x;
    {
        const int e_l = tid >> 4;             // 0..15
        const int a4  = (tid & 15) * 4;
        float4 w = *(const float4*)&W[(size_t)(es * 16 + e_l) * An + a4];
        tr[a4 + 0][e_l] = f2bf(w.x);
        tr[a4 + 1][e_l] = f2bf(w.y);
        tr[a4 + 2][e_l] = f2bf(w.z);
        tr[a4 + 3][e_l] = f2bf(w.w);
    }
    __syncthreads();
    {
        const int a  = tid >> 2;              // 0..63
        const int eo = (tid & 3) * 4;         // 0..12
        short4v v = { (short)tr[a][eo], (short)tr[a][eo + 1],
                      (short)tr[a][eo + 2], (short)tr[a][eo + 3] };
        *(short4v*)&W_t[(size_t)(m * 64 + a) * En + es * 16 + eo] = v;
    }
}

// ---------------------------------------------------------------------------
// Kernel 1: fused QKV projection, bf16 MFMA.  grid 512: blockIdx.x>>1 = 64-row
// block, &1 = column half (6 n-tiles each).  Wave w owns rows w*16..+15.
// Outputs: q bf16 [b][t][a] (pre-scaled 0.125), k bf16 [b][t][a],
//          v_t bf16 [b][a][t].
// ---------------------------------------------------------------------------
__global__ __launch_bounds__(256, 2) void proj_kernel(
    const float* __restrict__ emb, const unsigned short* __restrict__ W_t,
    const float* __restrict__ bq, const float* __restrict__ bk, const float* __restrict__ bv,
    unsigned short* __restrict__ q, unsigned short* __restrict__ k, unsigned short* __restrict__ v_t)
{
    const int tid  = threadIdx.x;
    const int wave = tid >> 6, lane = tid & 63, quad = lane >> 4, l15 = lane & 15;
    const int rb    = blockIdx.x >> 1;
    const int half  = blockIdx.x & 1;
    const int row0  = rb * 64;              // global row in [0, B*T)
    const int b     = row0 >> 12;
    const int trow0 = row0 & 4095;

    __shared__ unsigned short vtr[64 * 72];

    // A-fragments: emb rows (fp32 -> bf16), A[m=l15][k=quad*8+j]
    short8 A[8];
    {
        const float* erow = emb + (size_t)(row0 + wave * 16 + l15) * En;
#pragma unroll
        for (int c = 0; c < 8; c++) {
            const float* p = erow + c * 32 + quad * 8;
            float4 f0 = *(const float4*)p;
            float4 f1 = *(const float4*)(p + 4);
            A[c] = (short8){(short)f2bf(f0.x), (short)f2bf(f0.y), (short)f2bf(f0.z), (short)f2bf(f0.w),
                            (short)f2bf(f1.x), (short)f2bf(f1.y), (short)f2bf(f1.z), (short)f2bf(f1.w)};
        }
    }

    f32x4 acc[6];
#pragma unroll
    for (int i = 0; i < 6; i++) acc[i] = (f32x4){0.f, 0.f, 0.f, 0.f};

#pragma unroll
    for (int i = 0; i < 6; i++) {
        const int nt = half * 6 + i;
        const unsigned short* wb =
            W_t + (size_t)((nt >> 2) * 64 + (nt & 3) * 16 + l15) * En + quad * 8;
#pragma unroll
        for (int c = 0; c < 8; c++) {
            short8 bf = *(const short8*)(wb + c * 32);
            acc[i] = mfma16(A[c], bf, acc[i]);
        }
    }

    const float QS = 0.125f;   // 1/sqrt(A) folded into Q
#pragma unroll
    for (int i = 0; i < 6; i++) {
        const int nt = half * 6 + i;
        const int m  = nt >> 2;
        const int al = (nt & 3) * 16 + l15;
        const float bsv = ((m == 0) ? bq : (m == 1) ? bk : bv)[al];
#pragma unroll
        for (int rg = 0; rg < 4; rg++) {
            const int row_l = wave * 16 + quad * 4 + rg;   // C/D: row=quad*4+reg, col=l15
            const float val = acc[i][rg] + bsv;
            if (m == 0)      q[(size_t)(row0 + row_l) * An + al] = f2bf(val * QS);
            else if (m == 1) k[(size_t)(row0 + row_l) * An + al] = f2bf(val);
            else             vtr[al * 72 + row_l] = f2bf(val);
        }
    }
    if (half == 1) {
        __syncthreads();
        // flush V^T tile: v_t[b][a][t]
        const int a  = tid >> 2;
        const int tg = (tid & 3) * 16;
        unsigned short* dst = v_t + (size_t)(b * 64 + a) * Tn + trow0 + tg;
        *(short8*)dst       = *(const short8*)&vtr[a * 72 + tg];
        *(short8*)(dst + 8) = *(const short8*)&vtr[a * 72 + tg + 8];
    }
}

// ---------------------------------------------------------------------------
// Kernel 2: flash attention, bf16 MFMA, NO LDS staging / NO in-loop barriers.
// Each wave independently owns 32 q-rows; S^T = K Q^T orientation so softmax
// state is scalar/lane and the P transpose is done with in-register shuffles.
// grid (32*S, 4).  blockIdx.x = qblk*S + s; batches 2,3 reverse qblk order.
// Wave w of a block handles q-tile qblk_eff*4 + w  (32 rows each).
// Partials: Opart[(b*128+qt32)*S+s] = bf16 [32 qrow][64 a]; ml = m,l per row.
// ---------------------------------------------------------------------------
__global__ __launch_bounds__(256, 3) void flash_kernel(
    const unsigned short* __restrict__ q, const unsigned short* __restrict__ k,
    const unsigned short* __restrict__ v_t,
    unsigned short* __restrict__ Opart, float* __restrict__ ml,
    int S, int lgS)
{
    const int b    = blockIdx.y;
    const int qblk = blockIdx.x >> lgS;
    const int s    = blockIdx.x & (S - 1);
    const int qe   = (b >= 2) ? (31 - qblk) : qblk;

    const int tid  = threadIdx.x;
    const int wave = tid >> 6, lane = tid & 63, quad = lane >> 4, l15 = lane & 15;

    const int qt32  = qe * 4 + wave;       // 0..127 per batch
    const int qrow0 = qt32 * 32;
    const int tmax  = (qrow0 + 31) >> 6;

    __shared__ unsigned short tr[4][32 * 72];   // per-wave O transpose scratch

    // persistent Q B-fragments: B[k=a][n=qrow], group g = qcols 16g..16g+15
    short8 qB[2][2];
    {
        const unsigned short* qb = q + (((size_t)b << 12) + qrow0) * An;
#pragma unroll
        for (int g = 0; g < 2; g++)
#pragma unroll
            for (int c = 0; c < 2; c++)
                qB[g][c] = *(const short8*)(qb + (size_t)(16 * g + l15) * An + c * 32 + quad * 8);
    }

    float m_s[2] = {-__builtin_inff(), -__builtin_inff()};
    float l_s[2] = {0.f, 0.f};
    f32x4 O[4][2];
#pragma unroll
    for (int nt = 0; nt < 4; nt++)
#pragma unroll
        for (int g = 0; g < 2; g++) O[nt][g] = (f32x4){0.f, 0.f, 0.f, 0.f};

    const unsigned short* kb0 = k   + ((size_t)b << 12) * An;
    const unsigned short* vb0 = v_t + (size_t)b * An * Tn;

    for (int t = s; t <= tmax; t += S) {
        // ---- K A-fragments straight from cache ----
        short8 KA[4][2];
        {
            const unsigned short* kb = kb0 + (size_t)t * 64 * An;
#pragma unroll
            for (int nt = 0; nt < 4; nt++)
#pragma unroll
                for (int c = 0; c < 2; c++)
                    KA[nt][c] = *(const short8*)(kb + (size_t)(nt * 16 + l15) * An + c * 32 + quad * 8);
        }

        // ---- S^T = K Q^T : 16 MFMA.  S^T[kv=quad*4+rg (+16nt)][qrow=16g+l15]
        f32x4 St[4][2];
#pragma unroll
        for (int nt = 0; nt < 4; nt++)
#pragma unroll
            for (int g = 0; g < 2; g++) {
                f32x4 acc = (f32x4){0.f, 0.f, 0.f, 0.f};
                acc = mfma16(KA[nt][0], qB[g][0], acc);
                acc = mfma16(KA[nt][1], qB[g][1], acc);
                St[nt][g] = acc;
            }

        // ---- V^T A-fragments (issue early; consumed after softmax) ----
        short8 VA[4][2];
        {
            const unsigned short* vb = vb0 + (size_t)t * 64;
#pragma unroll
            for (int nt = 0; nt < 4; nt++)
#pragma unroll
                for (int c = 0; c < 2; c++)
                    VA[nt][c] = *(const short8*)(vb + (size_t)(nt * 16 + l15) * Tn + c * 32 + quad * 8);
        }

        // ---- causal mask on the diagonal tile ----
        if (t == tmax) {
            const int kvb = t * 64 + quad * 4;
#pragma unroll
            for (int nt = 0; nt < 4; nt++)
#pragma unroll
                for (int g = 0; g < 2; g++) {
                    const int qr = qrow0 + 16 * g + l15;
#pragma unroll
                    for (int rg = 0; rg < 4; rg++)
                        if (kvb + nt * 16 + rg > qr) St[nt][g][rg] = -__builtin_inff();
                }
        }

        // ---- online softmax + P pack (per qcol group g) ----
        unsigned int pk[2][4][2];
#pragma unroll
        for (int g = 0; g < 2; g++) {
            float mt = -__builtin_inff();
#pragma unroll
            for (int nt = 0; nt < 4; nt++) {
                mt = fmaxf(mt, fmaxf(fmaxf(St[nt][g][0], St[nt][g][1]),
                                     fmaxf(St[nt][g][2], St[nt][g][3])));
            }
            mt = fmaxf(mt, __shfl_xor(mt, 16));
            mt = fmaxf(mt, __shfl_xor(mt, 32));
            const float mn = fmaxf(m_s[g], mt);
            const float alpha = __expf(m_s[g] - mn);
            m_s[g] = mn;
            float rs = 0.f;
#pragma unroll
            for (int nt = 0; nt < 4; nt++) {
#pragma unroll
                for (int rg = 0; rg < 4; rg++) {
                    const float p = __expf(St[nt][g][rg] - mn);
                    St[nt][g][rg] = p;
                    rs += p;
                }
                pk[g][nt][0] = packbf2(St[nt][g][0], St[nt][g][1]);
                pk[g][nt][1] = packbf2(St[nt][g][2], St[nt][g][3]);
            }
            rs += __shfl_xor(rs, 16);
            rs += __shfl_xor(rs, 32);
            l_s[g] = l_s[g] * alpha + rs;
#pragma unroll
            for (int nt = 0; nt < 4; nt++)
#pragma unroll
                for (int rg = 0; rg < 4; rg++) O[nt][g][rg] *= alpha;
        }

        // ---- P^T B-fragments via shuffles; O^T += V^T P^T : 16 MFMA ----
#pragma unroll
        for (int g = 0; g < 2; g++)
#pragma unroll
            for (int c = 0; c < 2; c++) {
                int4v bd;
#pragma unroll
                for (int d = 0; d < 4; d++) {
                    const int src = (quad & 1) * 32 + (d >> 1) * 16 + l15;
                    const int v0 = __shfl((int)pk[g][2 * c][d & 1], src);
                    const int v1 = __shfl((int)pk[g][2 * c + 1][d & 1], src);
                    bd[d] = (quad & 2) ? v1 : v0;
                }
                const short8 pb = __builtin_bit_cast(short8, bd);
#pragma unroll
                for (int nt = 0; nt < 4; nt++)
                    O[nt][g] = mfma16(VA[nt][c], pb, O[nt][g]);
            }
    }

    // ---- epilogue: per-wave LDS transpose O^T -> [qrow][a], store bf16 ----
    {
        unsigned short* tw = tr[wave];
#pragma unroll
        for (int nt = 0; nt < 4; nt++)
#pragma unroll
            for (int g = 0; g < 2; g++)
#pragma unroll
                for (int rg = 0; rg < 4; rg++)
                    tw[(16 * g + l15) * 72 + nt * 16 + quad * 4 + rg] = f2bf(O[nt][g][rg]);
    }
    __syncthreads();
    {
        const size_t unit = ((size_t)(b * 128 + qt32) * (size_t)S + s);
        unsigned short* ob = Opart + unit * 2048;
        const unsigned short* tw = tr[wave];
        const int row = lane >> 1;
#pragma unroll
        for (int p = 0; p < 4; p++) {
            const int colh = (lane & 1) * 8 + p * 16;
            *(short8*)(ob + row * 64 + colh) = *(const short8*)&tw[row * 72 + colh];
        }
        if (quad == 0) {
            float* mlb = ml + unit * 64;
#pragma unroll
            for (int g = 0; g < 2; g++) {
                mlb[16 * g + l15]      = m_s[g];
                mlb[32 + 16 * g + l15] = l_s[g];
            }
        }
    }
}

// ---------------------------------------------------------------------------
// Kernel 3: merge the S kv-stripe partials -> out fp32 [b][t][a].
// grid (128, 4): per (b, qt32).  Thread: qrow = tid>>3, a8 = (tid&7)*8.
// ---------------------------------------------------------------------------
__global__ __launch_bounds__(256) void merge_kernel(
    const unsigned short* __restrict__ Opart, const float* __restrict__ ml,
    float* __restrict__ out, int S)
{
    const int qt32 = blockIdx.x, b = blockIdx.y;
    const int tid  = threadIdx.x;
    const int qr   = tid >> 3;           // 0..31
    const int a8   = (tid & 7) * 8;
    const size_t ub = (size_t)(b * 128 + qt32) * (size_t)S;

    float mstar = -__builtin_inff();
    for (int s = 0; s < S; s++)
        mstar = fmaxf(mstar, ml[(ub + s) * 64 + qr]);

    float acc[8];
#pragma unroll
    for (int j = 0; j < 8; j++) acc[j] = 0.f;
    float lsum = 0.f;

    for (int s = 0; s < S; s++) {
        const float ms = ml[(ub + s) * 64 + qr];
        const float ls = ml[(ub + s) * 64 + 32 + qr];
        const float w  = __expf(ms - mstar);
        lsum += ls * w;
        const short8 ov = *(const short8*)&Opart[(ub + s) * 2048 + qr * 64 + a8];
#pragma unroll
        for (int j = 0; j < 8; j++) acc[j] += w * bf2f((unsigned short)ov[j]);
    }
    const float inv = 1.f / lsum;
    float* op = out + (((size_t)b << 12) + qt32 * 32 + qr) * An + a8;
    float4 r0 = {acc[0] * inv, acc[1] * inv, acc[2] * inv, acc[3] * inv};
    float4 r1 = {acc[4] * inv, acc[5] * inv, acc[6] * inv, acc[7] * inv};
    *(float4*)op       = r0;
    *(float4*)(op + 4) = r1;
}

// ---------------------------------------------------------------------------
extern "C" void kernel_launch(void* const* d_in, const int* in_sizes, int n_in,
                              void* d_out, int out_size, void* d_ws, size_t ws_size,
                              hipStream_t stream) {
    const float* emb = (const float*)d_in[0];
    const float* Wk  = (const float*)d_in[1];
    const float* bk  = (const float*)d_in[2];
    const float* Wq  = (const float*)d_in[3];
    const float* bq  = (const float*)d_in[4];
    const float* Wv  = (const float*)d_in[5];
    const float* bv  = (const float*)d_in[6];
    float* out = (float*)d_out;

    char* ws = (char*)d_ws;
    const size_t MB = 1024 * 1024;

    // pick stripe count S from available workspace
    int S = 1, lgS = 0;
    for (int cand = 8; cand >= 1; cand >>= 1) {
        const size_t need = 6 * MB + 128 * 1024                  // q,k,v_t,W_t
                          + (size_t)cand * 128 * 1024            // ml
                          + (size_t)cand * 2 * MB;               // Opart
        if (need <= ws_size) {
            S = cand;
            lgS = (cand == 8) ? 3 : (cand == 4) ? 2 : (cand == 2) ? 1 : 0;
            break;
        }
    }

    unsigned short* q     = (unsigned short*)(ws);                         // 2 MB
    unsigned short* k     = (unsigned short*)(ws + 2 * MB);                // 2 MB
    unsigned short* v_t   = (unsigned short*)(ws + 4 * MB);                // 2 MB
    unsigned short* W_t   = (unsigned short*)(ws + 6 * MB);                // 96 KB
    float*          ml    = (float*)(ws + 6 * MB + 128 * 1024);            // S*128 KB
    unsigned short* Opart = (unsigned short*)(ws + 6 * MB + 128 * 1024 + (size_t)S * 128 * 1024);

    prep_kernel<<<dim3(3, 16), 256, 0, stream>>>(Wq, Wk, Wv, W_t);
    proj_kernel<<<512, 256, 0, stream>>>(emb, W_t, bq, bk, bv, q, k, v_t);
    flash_kernel<<<dim3(32 * S, 4), 256, 0, stream>>>(q, k, v_t, Opart, ml, S, lgS);
    merge_kernel<<<dim3(128, 4), 256, 0, stream>>>(Opart, ml, out, S);
}